// Round 8
// baseline (188.396 us; speedup 1.0000x reference)
//
#include <hip/hip_runtime.h>
#include <stdint.h>

#define DN 128
#define AN 128
#define HN 4
#define FN 128
#define L2N 50
#define NPOS (64*200)
#define NEGC (-4294967295.0f)

// ws layout (4B units)
#define OFF_MTWB 0         // u32 [40 tn][4 kk][64 lane][4 jj] : B-frag MT|Wf pairs along dd
#define OFF_GTB  40960     // u32 [8 tn][16 kk][64 lane][4 jj] : B-frag GT pairs along flat hd
#define OFF_CB   73728     // f32 [640] : 0..511 = Wk_h^T bq ; 512..639 = bv@Wf+bf
#define OFF_U    74368     // u32 [12800][256] : u as half2 pairs along outc
#define OFF_R    3351168   // f32 [12800][128] : qe@Wf + B0
#define OFF_PV   4989568   // u32 [12800][256] : pv as half2 pairs, flat hd

typedef __fp16 half2v __attribute__((ext_vector_type(2)));
typedef __fp16 f16x8  __attribute__((ext_vector_type(8)));
typedef float  f32x4  __attribute__((ext_vector_type(4)));
union frg { uint4 u; f16x8 h; };

__device__ __forceinline__ float dot2(uint32_t a, uint32_t b, float c) {
#if __has_builtin(__builtin_amdgcn_fdot2)
    union { uint32_t u; half2v h; } ca, cb; ca.u = a; cb.u = b;
    return __builtin_amdgcn_fdot2(ca.h, cb.h, c, false);
#else
    union { uint32_t u; _Float16 h[2]; } ca, cb; ca.u = a; cb.u = b;
    return c + (float)ca.h[0]*(float)cb.h[0] + (float)ca.h[1]*(float)cb.h[1];
#endif
}
__device__ __forceinline__ uint32_t packh2(float x, float y) {   // RTNE
    union { _Float16 h[2]; uint32_t u; } c; c.h[0] = (_Float16)x; c.h[1] = (_Float16)y;
    return c.u;
}

// ================= K0: fold weights — all heavy loads LDS-staged, coalesced =================
__global__ __launch_bounds__(256) void k0_pre(
    const float* __restrict__ Wq, const float* __restrict__ bq,
    const float* __restrict__ Wk, const float* __restrict__ bk,
    const float* __restrict__ Wv, const float* __restrict__ bv,
    const float* __restrict__ Wf, const float* __restrict__ bfb,
    float* __restrict__ ws)
{
    uint32_t* MTWB = (uint32_t*)ws + OFF_MTWB;
    uint32_t* GTBw = (uint32_t*)ws + OFF_GTB;
    float*    CB   = ws + OFF_CB;
    const int b = blockIdx.x, t = threadIdx.x;

    if (b < 128) {                 // MT_h = Wq_h @ Wk_h^T : tn = b>>2, kk = b&3
        __shared__ float Aq[32][33];
        __shared__ float Ak[16][33];
        const int tn = b >> 2, kk = b & 3;
        const int h = tn >> 3;
        for (int i = t >> 5; i < 32; i += 8)
            Aq[i][t & 31] = Wq[(32*kk + i)*AN + h*32 + (t & 31)];
        for (int i = t >> 5; i < 16; i += 8)
            Ak[i][t & 31] = Wk[((tn & 7)*16 + i)*AN + h*32 + (t & 31)];
        __syncthreads();
        const int lane = t >> 2, jj = t & 3;
        const int dl0 = 8*(lane >> 4) + 2*jj;
        const int ol  = lane & 15;
        float s0 = 0.f, s1 = 0.f;
        #pragma unroll 8
        for (int j = 0; j < 32; ++j) {
            float wkv = Ak[ol][j];
            s0 += Aq[dl0][j]*wkv;
            s1 += Aq[dl0+1][j]*wkv;
        }
        MTWB[b*256 + t] = packh2(s0, s1);
    } else if (b < 256) {          // GT_h = Wv_h @ Wf_h : g = b-128, tn = g>>4, kk = g&15
        __shared__ float Vv[32][33];
        __shared__ float Wl[32][17];
        const int g = b - 128, tn = g >> 4, kk = g & 15;
        const int h = kk >> 2;
        for (int i = t >> 5; i < 32; i += 8)
            Vv[i][t & 31] = Wv[(32*(kk & 3) + i)*AN + h*32 + (t & 31)];
        for (int i = t; i < 512; i += 256) {
            int a0 = i >> 4, fl = i & 15;
            Wl[a0][fl] = Wf[(h*32 + a0)*FN + tn*16 + fl];
        }
        __syncthreads();
        const int lane = t >> 2, jj = t & 3;
        const int dl0 = 8*(lane >> 4) + 2*jj;
        const int fl  = lane & 15;
        float s0 = 0.f, s1 = 0.f;
        #pragma unroll 8
        for (int a = 0; a < 32; ++a) {
            float wfv = Wl[a][fl];
            s0 += Vv[dl0][a]*wfv;
            s1 += Vv[dl0+1][a]*wfv;
        }
        GTBw[g*256 + t] = packh2(s0, s1);
    } else if (b == 256) {         // Wf pairs -> MTWB cols 512..639 (coalesced loads)
        const int f = t & 127;
        const int d0 = (t >> 7)*32;
        for (int dd2 = d0; dd2 < d0 + 32; ++dd2) {
            uint32_t v = packh2(Wf[(2*dd2)*FN + f], Wf[(2*dd2+1)*FN + f]);
            int tn = 32 + (f >> 4);
            int lane = ((dd2 >> 2) & 3)*16 + (f & 15);
            MTWB[tn*1024 + (dd2 >> 4)*256 + lane*4 + (dd2 & 3)] = v;
        }
    } else {                       // b == 257: CB (stage all of Wk in LDS)
        __shared__ float WkL[128][129];
        for (int i4 = t; i4 < 4096; i4 += 256) {
            float4 v = *(const float4*)(Wk + i4*4);
            int d = (i4*4) >> 7, col = (i4*4) & 127;
            WkL[d][col]   = v.x; WkL[d][col+1] = v.y;
            WkL[d][col+2] = v.z; WkL[d][col+3] = v.w;
        }
        __syncthreads();
        for (int c = t; c < 512; c += 256) {
            int h = c >> 7, d = c & 127;
            float s = 0.f;
            #pragma unroll 8
            for (int j = 0; j < 32; ++j) s += WkL[d][h*32 + j]*bq[h*32 + j];
            CB[c] = s;
        }
        if (t < 128) {             // B0 = bv@Wf + bf (coalesced along f)
            float s = bfb[t];
            for (int a = 0; a < AN; ++a) s += bv[a]*Wf[a*FN + t];
            CB[512 + t] = s;
        }
    }
}

// ================= K1: MFMA GEMM  U|R = qe @ [MT|Wf] + CB (unchanged) =================
__global__ __launch_bounds__(256) void k1_proj(
    const int* __restrict__ queries, const float* __restrict__ E,
    float* __restrict__ ws)
{
    const uint32_t* MTWB = (const uint32_t*)ws + OFF_MTWB;
    const float*    CB   = ws + OFF_CB;
    uint32_t* U = (uint32_t*)ws + OFF_U;
    float*    R = ws + OFF_R;

    const int t = threadIdx.x, wv = t >> 6, ln = t & 63;
    const int W  = blockIdx.x*4 + wv;
    const int tm = W / 5, g = W - tm*5;
    const int m = ln & 15, q = ln >> 4;
    const int pos0 = tm*16 + q*4;

    const int qidx = queries[tm*16 + m];
    const float* Eq = E + (size_t)qidx * DN;

    frg a[4];
    #pragma unroll
    for (int kk = 0; kk < 4; ++kk) {
        float4 e0 = *(const float4*)(Eq + kk*32 + q*8);
        float4 e1 = *(const float4*)(Eq + kk*32 + q*8 + 4);
        a[kk].u.x = packh2(e0.x, e0.y);
        a[kk].u.y = packh2(e0.z, e0.w);
        a[kk].u.z = packh2(e1.x, e1.y);
        a[kk].u.w = packh2(e1.z, e1.w);
    }

    #pragma unroll 1
    for (int i = 0; i < 8; ++i) {
        const int tn = g*8 + i;
        const float cb = CB[tn*16 + m];
        f32x4 c = {cb, cb, cb, cb};
        #pragma unroll
        for (int kk = 0; kk < 4; ++kk) {
            frg b; b.u = *(const uint4*)(MTWB + ((size_t)(tn*4 + kk)*64 + ln)*4);
            c = __builtin_amdgcn_mfma_f32_16x16x32_f16(a[kk].h, b.h, c, 0, 0, 0);
        }
        if (tn < 32) {
            float p0 = __shfl_xor(c[0], 1);
            float p1 = __shfl_xor(c[1], 1);
            float p2 = __shfl_xor(c[2], 1);
            float p3 = __shfl_xor(c[3], 1);
            if ((ln & 1) == 0) {
                const int ucol = tn*8 + (m >> 1);
                U[(size_t)(pos0+0)*256 + ucol] = packh2(c[0], p0);
                U[(size_t)(pos0+1)*256 + ucol] = packh2(c[1], p1);
                U[(size_t)(pos0+2)*256 + ucol] = packh2(c[2], p2);
                U[(size_t)(pos0+3)*256 + ucol] = packh2(c[3], p3);
            }
        } else {
            const int f = (tn - 32)*16 + m;
            R[(size_t)(pos0+0)*128 + f] = c[0];
            R[(size_t)(pos0+1)*128 + f] = c[1];
            R[(size_t)(pos0+2)*128 + f] = c[2];
            R[(size_t)(pos0+3)*128 + f] = c[3];
        }
    }
}

// ================= K2: attention — MFMA scores, dot2 PV, 1 wave/pos =================
__global__ __launch_bounds__(128) void k2_attn(
    const int* __restrict__ keys, const float* __restrict__ E,
    float* __restrict__ ws)
{
    __shared__ uint32_t kT[2][64][51];                  // [pos][dp][r] f16 d-pairs
    __shared__ __align__(16) uint32_t attnP[2][32][4];  // [pos][r2][h] f16 r-pairs

    const uint32_t* U  = (const uint32_t*)ws + OFF_U;
    uint32_t*       PV = (uint32_t*)ws + OFF_PV;

    const int t = threadIdx.x, wv = t >> 6, ln = t & 63;
    const int pos = blockIdx.x*2 + wv;
    const int m16 = ln & 15, q = ln >> 4;
    const int* kp = keys + (size_t)pos * L2N;

    // B-fragments for score MFMAs: cols 0..3 = heads (from U), col 4 = ones (ksum), rest 0
    frg bu[4];
    #pragma unroll
    for (int kk = 0; kk < 4; ++kk) {
        if (m16 < 4)
            bu[kk].u = *(const uint4*)(U + (size_t)pos*256 + m16*64 + kk*16 + q*4);
        else if (m16 == 4)
            bu[kk].u = make_uint4(0x3C003C00u, 0x3C003C00u, 0x3C003C00u, 0x3C003C00u);
        else
            bu[kk].u = make_uint4(0u, 0u, 0u, 0u);
    }

    // Gather 50 rows (lane = d-pair); keep r-pair-packed copies in regs for PV
    uint32_t klo2[25], khi2[25];
    {
        float2 a0 = *(const float2*)(E + (size_t)kp[0]*DN + 2*ln);
        float2 a1 = *(const float2*)(E + (size_t)kp[1]*DN + 2*ln);
        float2 b0 = *(const float2*)(E + (size_t)kp[2]*DN + 2*ln);
        float2 b1 = *(const float2*)(E + (size_t)kp[3]*DN + 2*ln);
        #pragma unroll
        for (int r2 = 0; r2 < 25; ++r2) {
            float2 c0 = a0, c1 = a1;
            a0 = b0; a1 = b1;
            if (r2 < 23) {
                b0 = *(const float2*)(E + (size_t)kp[2*r2+4]*DN + 2*ln);
                b1 = *(const float2*)(E + (size_t)kp[2*r2+5]*DN + 2*ln);
            }
            uint32_t ka = packh2(c0.x, c0.y);
            uint32_t kb = packh2(c1.x, c1.y);
            kT[wv][ln][2*r2]   = ka;
            kT[wv][ln][2*r2+1] = kb;
            klo2[r2] = (ka & 0xFFFFu) | (kb << 16);
            khi2[r2] = (ka >> 16)     | (kb & 0xFFFF0000u);
        }
    }
    __syncthreads();

    // Scores: 4 m-tiles (rows 16t..16t+15) x 4 k-steps; D[m=r][n] = QK^T | ksum
    f32x4 cc[4] = {{0,0,0,0},{0,0,0,0},{0,0,0,0},{0,0,0,0}};
    #pragma unroll
    for (int kk = 0; kk < 4; ++kk) {
        const int dp0 = kk*16 + q*4;
        #pragma unroll
        for (int tt = 0; tt < 4; ++tt) {
            frg a;
            const int r = tt*16 + m16;       // rows >= 50 read benign LDS garbage, masked below
            a.u.x = kT[wv][dp0+0][r];
            a.u.y = kT[wv][dp0+1][r];
            a.u.z = kT[wv][dp0+2][r];
            a.u.w = kT[wv][dp0+3][r];
            cc[tt] = __builtin_amdgcn_mfma_f32_16x16x32_f16(a.h, bu[kk].h, cc[tt], 0, 0, 0);
        }
    }

    // Mask + softmax in D-layout (head = lane column n; ksum at column 4)
    float w[4][4];
    {
        float sc[4][4];
        #pragma unroll
        for (int tt = 0; tt < 4; ++tt)
            #pragma unroll
            for (int rg = 0; rg < 4; ++rg) {
                float kv = __shfl(cc[tt][rg], (ln & 48) | 4);     // ksum for this row
                float s  = cc[tt][rg] * 0.17677669529663687f;     // 1/sqrt(32)
                s = (kv == 0.0f) ? NEGC : s;
                int r = tt*16 + q*4 + rg;
                sc[tt][rg] = (r < L2N) ? s : -__builtin_inff();
            }
        float mx = sc[0][0];
        #pragma unroll
        for (int tt = 0; tt < 4; ++tt)
            #pragma unroll
            for (int rg = 0; rg < 4; ++rg) mx = fmaxf(mx, sc[tt][rg]);
        mx = fmaxf(mx, __shfl_xor(mx, 16));
        mx = fmaxf(mx, __shfl_xor(mx, 32));
        float sum = 0.f;
        #pragma unroll
        for (int tt = 0; tt < 4; ++tt)
            #pragma unroll
            for (int rg = 0; rg < 4; ++rg) {
                float e = __expf(sc[tt][rg] - mx);
                w[tt][rg] = e;
                sum += e;
            }
        sum += __shfl_xor(sum, 16);
        sum += __shfl_xor(sum, 32);
        float inv = 1.0f / sum;
        #pragma unroll
        for (int tt = 0; tt < 4; ++tt)
            #pragma unroll
            for (int rg = 0; rg < 4; ++rg) w[tt][rg] *= inv;
    }

    // Stash attn weights as r-pairs (same-wave cross-lane; no barrier needed)
    if (m16 < 4) {
        #pragma unroll
        for (int tt = 0; tt < 4; ++tt) {
            attnP[wv][8*tt + 2*q    ][m16] = packh2(w[tt][0], w[tt][1]);
            attnP[wv][8*tt + 2*q + 1][m16] = packh2(w[tt][2], w[tt][3]);
        }
    }

    // PV: dot2 over r-pairs; k held in registers from the gather
    {
        float l0=0,l1=0,l2=0,l3=0,h0=0,h1=0,h2=0,h3=0;
        #pragma unroll
        for (int r2 = 0; r2 < 25; ++r2) {
            uint4 wp = *(const uint4*)&attnP[wv][r2][0];
            uint32_t lo = klo2[r2], hi = khi2[r2];
            l0 = dot2(lo, wp.x, l0); h0 = dot2(hi, wp.x, h0);
            l1 = dot2(lo, wp.y, l1); h1 = dot2(hi, wp.y, h1);
            l2 = dot2(lo, wp.z, l2); h2 = dot2(hi, wp.z, h2);
            l3 = dot2(lo, wp.w, l3); h3 = dot2(hi, wp.w, h3);
        }
        uint32_t* PVp = PV + (size_t)pos*256;
        PVp[0*64 + ln] = packh2(l0, h0);
        PVp[1*64 + ln] = packh2(l1, h1);
        PVp[2*64 + ln] = packh2(l2, h2);
        PVp[3*64 + ln] = packh2(l3, h3);
    }
}

// ================= K3: MFMA GEMM  out = PV @ GT + R (unchanged) =================
__global__ __launch_bounds__(256) void k3_out(
    const float* __restrict__ ws, float* __restrict__ out)
{
    const uint32_t* GTB = (const uint32_t*)ws + OFF_GTB;
    const uint32_t* PV  = (const uint32_t*)ws + OFF_PV;
    const float*    R   = ws + OFF_R;

    const int t = threadIdx.x, wv = t >> 6, ln = t & 63;
    const int W  = blockIdx.x*4 + wv;
    const int tm = W >> 2, g = W & 3;
    const int m = ln & 15, q = ln >> 4;
    const int pos0 = tm*16 + q*4;

    frg a[16];
    const uint32_t* PVa = PV + (size_t)(tm*16 + m)*256;
    #pragma unroll
    for (int kk = 0; kk < 16; ++kk)
        a[kk].u = *(const uint4*)(PVa + kk*16 + q*4);

    #pragma unroll 1
    for (int i = 0; i < 2; ++i) {
        const int nt = g*2 + i;
        const int f = nt*16 + m;
        f32x4 c;
        c[0] = R[(size_t)(pos0+0)*128 + f];
        c[1] = R[(size_t)(pos0+1)*128 + f];
        c[2] = R[(size_t)(pos0+2)*128 + f];
        c[3] = R[(size_t)(pos0+3)*128 + f];
        #pragma unroll
        for (int kk = 0; kk < 16; ++kk) {
            frg b; b.u = *(const uint4*)(GTB + ((size_t)(nt*16 + kk)*64 + ln)*4);
            c = __builtin_amdgcn_mfma_f32_16x16x32_f16(a[kk].h, b.h, c, 0, 0, 0);
        }
        out[(size_t)(pos0+0)*128 + f] = c[0];
        out[(size_t)(pos0+1)*128 + f] = c[1];
        out[(size_t)(pos0+2)*128 + f] = c[2];
        out[(size_t)(pos0+3)*128 + f] = c[3];
    }
}

extern "C" void kernel_launch(void* const* d_in, const int* in_sizes, int n_in,
                              void* d_out, int out_size, void* d_ws, size_t ws_size,
                              hipStream_t stream) {
    const int* queries = (const int*)d_in[0];
    const int* keys    = (const int*)d_in[1];
    const float* E   = (const float*)d_in[2];
    const float* Wq  = (const float*)d_in[3];
    const float* bq  = (const float*)d_in[4];
    const float* Wk  = (const float*)d_in[5];
    const float* bk  = (const float*)d_in[6];
    const float* Wv  = (const float*)d_in[7];
    const float* bv  = (const float*)d_in[8];
    const float* Wf  = (const float*)d_in[9];
    const float* bfb = (const float*)d_in[10];
    float* ws = (float*)d_ws;
    float* o  = (float*)d_out;

    hipLaunchKernelGGL(k0_pre,  dim3(258),  dim3(256), 0, stream,
                       Wq, bq, Wk, bk, Wv, bv, Wf, bfb, ws);
    hipLaunchKernelGGL(k1_proj, dim3(1000), dim3(256), 0, stream, queries, E, ws);
    hipLaunchKernelGGL(k2_attn, dim3(6400), dim3(128), 0, stream, keys, E, ws);
    hipLaunchKernelGGL(k3_out,  dim3(800),  dim3(256), 0, stream, ws, o);
}